// Round 4
// baseline (469.807 us; speedup 1.0000x reference)
//
#include <hip/hip_runtime.h>

// DeltaNet fused pipeline, round 9:
//   k_cast:    x fp32 -> bf16
//   k_transw:  Wq/Wk/Wv -> Wt (N x K bf16), Wo -> Wot, Wg -> Wgt16 (z==4)
//   k_gemm:    bf16 MFMA 128x128 GEMM (round-5 proven, 120us QKV), BK=64,
//              global_load_lds(16B) staging with XOR bank-swizzle
//   k_gemm2:   256x128 triple-buffered GEMM (out-proj only; 256 blocks = 1
//              exact occupancy round)
//   k_betaW:   wave-per-row dot: beta = clip(sigmoid(xb . Wgt16[h] + bg))
//   k_prep:    G-scan + RoPE + phi + scale + K^T transpose + intra-chunk A
//   k_scan:    REWRITTEN: one block per bh (grid 32, 512 thr, 8 waves); each
//              wave owns a 16-col e-slice. Q/K/A/V staged ONCE per chunk
//              (was 8x redundant across eb-blocks: 344MB -> 57MB), denom
//              computed once into invs[64], z once. 3 barriers/chunk.

typedef __attribute__((ext_vector_type(8))) short short8;
typedef __attribute__((ext_vector_type(4))) float f32x4;

__device__ __forceinline__ unsigned short f2bf(float f) {
  unsigned u = __float_as_uint(f);
  u += 0x7fffu + ((u >> 16) & 1u);   // RNE
  return (unsigned short)(u >> 16);
}
__device__ __forceinline__ float bf2f(unsigned short s) {
  return __uint_as_float(((unsigned)s) << 16);
}
__device__ __forceinline__ float phi_elu1(float x) {
  return x > 0.f ? x + 1.f : expf(x);
}
// async global->LDS, 16B per lane; LDS dest = wave-uniform base + lane*16.
__device__ __forceinline__ void gl_lds16(const void* g, void* l) {
  __builtin_amdgcn_global_load_lds(
      (const __attribute__((address_space(1))) void*)g,
      (__attribute__((address_space(3))) void*)l, 16, 0, 0);
}
// raw workgroup barrier: does NOT drain vmcnt.
__device__ __forceinline__ void bar_raw() {
  asm volatile("" ::: "memory");
  __builtin_amdgcn_s_barrier();
  asm volatile("" ::: "memory");
}

// ---------------- cast x -> bf16 ----------------
__global__ __launch_bounds__(256)
void k_cast(const float* __restrict__ x, unsigned short* __restrict__ xb) {
  int i = (blockIdx.x * 256 + threadIdx.x) * 4;
  float4 f = *(const float4*)(x + i);
  uint2 p;
  p.x = (unsigned)f2bf(f.x) | ((unsigned)f2bf(f.y) << 16);
  p.y = (unsigned)f2bf(f.z) | ((unsigned)f2bf(f.w) << 16);
  *(uint2*)(xb + i) = p;
}

// ---------------- transpose+cast weights ----------------
// z 0..3: W (K x N) -> (N x K) bf16. z==4: Wg (2048x16) -> Wgt16 (16x2048).
__global__ __launch_bounds__(256)
void k_transw(const float* __restrict__ Wq, const float* __restrict__ Wk,
              const float* __restrict__ Wv, const float* __restrict__ Wo,
              const float* __restrict__ Wg,
              unsigned short* __restrict__ Wt, unsigned short* __restrict__ Wot,
              unsigned short* __restrict__ Wgt16) {
  const int z = blockIdx.z;
  if (z == 4) {
    if (blockIdx.y != 0) return;
    int idx = blockIdx.x * 256 + threadIdx.x;  // 8192 threads
    int h = idx >> 9, k4 = (idx & 511) * 4;
    uint2 p;
    p.x = (unsigned)f2bf(Wg[(k4 + 0) * 16 + h]) | ((unsigned)f2bf(Wg[(k4 + 1) * 16 + h]) << 16);
    p.y = (unsigned)f2bf(Wg[(k4 + 2) * 16 + h]) | ((unsigned)f2bf(Wg[(k4 + 3) * 16 + h]) << 16);
    *(uint2*)(Wgt16 + (size_t)h * 2048 + k4) = p;
    return;
  }
  const float* W = (z == 0) ? Wq : (z == 1) ? Wk : (z == 2) ? Wv : Wo;
  unsigned short* out = (z < 3) ? (Wt + (size_t)z * 2048 * 2048) : Wot;
  __shared__ float tile[64][65];
  const int n0 = blockIdx.x * 64;
  const int k0 = blockIdx.y * 64;
  const int tx = threadIdx.x & 63;
  const int ty = threadIdx.x >> 6;
#pragma unroll
  for (int rl = 0; rl < 16; ++rl) {
    int kk = rl * 4 + ty;
    tile[kk][tx] = W[(size_t)(k0 + kk) * 2048 + n0 + tx];
  }
  __syncthreads();
#pragma unroll
  for (int rl = 0; rl < 16; ++rl) {
    int nn = rl * 4 + ty;
    out[(size_t)(n0 + nn) * 2048 + k0 + tx] = f2bf(tile[tx][nn]);
  }
}

// ---------------- beta: wave-per-row bf16 dot + sigmoid + clip ----------------
__global__ __launch_bounds__(256)
void k_betaW(const unsigned short* __restrict__ xb, const unsigned short* __restrict__ Wgt16,
             const float* __restrict__ bg, float* __restrict__ beta) {
  const int w = threadIdx.x >> 6;
  const int lane = threadIdx.x & 63;
  const int m = blockIdx.x * 4 + w;
  const int h = lane & 15, kq = lane >> 4;
  const unsigned short* xr = xb + (size_t)m * 2048 + kq * 512;
  const unsigned short* wr = Wgt16 + (size_t)h * 2048 + kq * 512;
  float acc = 0.f;
#pragma unroll 8
  for (int i = 0; i < 64; ++i) {
    short8 xv = *(const short8*)(xr + i * 8);
    short8 wv = *(const short8*)(wr + i * 8);
#pragma unroll
    for (int j = 0; j < 8; ++j)
      acc = fmaf(bf2f((unsigned short)xv[j]), bf2f((unsigned short)wv[j]), acc);
  }
  acc += __shfl_xor(acc, 16, 64);
  acc += __shfl_xor(acc, 32, 64);
  if (lane < 16) {
    float v = acc + bg[h];
    float bv = 1.f / (1.f + expf(-v));
    beta[(size_t)m * 16 + h] = fminf(fmaxf(bv, 0.8f), 0.9995f);
  }
}

// ---------------- bf16 MFMA GEMM 128x128 (round-5 proven; QKV) ----------------
template <bool OUT_BF16, bool ADD_BIAS>
__global__ __launch_bounds__(256)
void k_gemm(const unsigned short* __restrict__ A, const unsigned short* __restrict__ Bt,
            void* __restrict__ Cptr, const float* __restrict__ bias,
            int M, int N, int K, int ldA, int ldC) {
  __shared__ __align__(16) unsigned short As[128][64];  // 16KB
  __shared__ __align__(16) unsigned short Bs[128][64];  // 16KB
  const int tid = threadIdx.x;
  const int n0 = blockIdx.x * 128;
  const int m0 = blockIdx.y * 128;
  const int lane = tid & 63;
  const int w = tid >> 6;
  const int wm = w >> 1, wn = w & 1;
  const int q = lane >> 4, r = lane & 15;

  const int srow0 = w * 8 + (lane >> 3);
  const int scol = ((lane & 7) ^ ((lane >> 3) & 7)) * 8;

  f32x4 acc[4][4];
#pragma unroll
  for (int i = 0; i < 4; ++i)
#pragma unroll
    for (int j = 0; j < 4; ++j) acc[i][j] = (f32x4){0.f, 0.f, 0.f, 0.f};

  const unsigned short* A0 = A + (size_t)(m0 + srow0) * ldA + scol;
  const unsigned short* B0 = Bt + (size_t)(n0 + srow0) * K + scol;
  unsigned short* lA = &As[srow0][(lane & 7) * 8];
  unsigned short* lB = &Bs[srow0][(lane & 7) * 8];

  const int rsw = r & 7;

  for (int kt = 0; kt < K; kt += 64) {
    __syncthreads();
#pragma unroll
    for (int i = 0; i < 4; ++i) {
      gl_lds16(A0 + (size_t)i * 32 * ldA + kt, lA + i * 2048);
      gl_lds16(B0 + (size_t)i * 32 * K + kt, lB + i * 2048);
    }
    __syncthreads();
#pragma unroll
    for (int kk = 0; kk < 2; ++kk) {
      const int ps = ((kk * 4 + q) ^ rsw) * 8;
      short8 af[4], bfr[4];
#pragma unroll
      for (int i = 0; i < 4; ++i)
        af[i] = *(const short8*)&As[wm * 64 + i * 16 + r][ps];
#pragma unroll
      for (int j = 0; j < 4; ++j)
        bfr[j] = *(const short8*)&Bs[wn * 64 + j * 16 + r][ps];
#pragma unroll
      for (int i = 0; i < 4; ++i)
#pragma unroll
        for (int j = 0; j < 4; ++j)
          acc[i][j] = __builtin_amdgcn_mfma_f32_16x16x32_bf16(af[i], bfr[j], acc[i][j], 0, 0, 0);
    }
  }
#pragma unroll
  for (int i = 0; i < 4; ++i) {
#pragma unroll
    for (int j = 0; j < 4; ++j) {
#pragma unroll
      for (int rr = 0; rr < 4; ++rr) {
        int mi = m0 + wm * 64 + i * 16 + q * 4 + rr;
        int ni = n0 + wn * 64 + j * 16 + r;
        float val = acc[i][j][rr];
        if (ADD_BIAS) val += bias[ni];
        if (OUT_BF16)
          ((unsigned short*)Cptr)[(size_t)mi * ldC + ni] = f2bf(val);
        else
          ((float*)Cptr)[(size_t)mi * ldC + ni] = val;
      }
    }
  }
}

// ---------------- bf16 MFMA GEMM 256x128, triple-buffered (out-proj) ----------------
template <bool OUT_BF16, bool ADD_BIAS>
__global__ __launch_bounds__(512, 2)
void k_gemm2(const unsigned short* __restrict__ A, const unsigned short* __restrict__ Bt,
             void* __restrict__ Cptr, const float* __restrict__ bias,
             int M, int N, int K, int ldA, int ldC) {
  __shared__ __align__(16) unsigned short Ls[3][3][128][64];  // 144KB
  const int tid = threadIdx.x;
  const int lane = tid & 63;
  const int w = tid >> 6;    // 0..7
  const int wm = w >> 1;     // 0..3  (64-row slice of the 256 M-tile)
  const int wn = w & 1;      // 0..1  (64-col slice of the 128 N-tile)
  const int ql = lane >> 4;  // 0..3
  const int r = lane & 15;

  // bijective XCD swizzle (nwg % 8 == 0: 256).
  const int nwg = gridDim.x * gridDim.y;
  const int orig = blockIdx.y * gridDim.x + blockIdx.x;
  const int li = (orig & 7) * (nwg >> 3) + (orig >> 3);
  const int m0 = (li & 15) * 256;   // gridDim.x == 16 (M/256)
  const int n0 = (li >> 4) * 128;

  const int srow = tid >> 3;   // 0..63
  const int sphys = tid & 7;
  const int slog = sphys ^ (srow & 7);
  const unsigned short* Ab = A + (size_t)(m0 + srow) * ldA + slog * 8;
  const unsigned short* Bb = Bt + (size_t)(n0 + srow) * K + slog * 8;

#define STG(st, h, tt)                                                        \
  do {                                                                        \
    const size_t ldx = ((h) == 2) ? (size_t)K : (size_t)ldA;                  \
    const unsigned short* gs =                                                \
        (((h) == 2) ? Bb : (Ab + (size_t)((h) * 128) * ldA)) +                \
        (size_t)(tt) * 64;                                                    \
    unsigned short* ld = &Ls[(st)][(h)][srow][sphys * 8];                     \
    gl_lds16(gs, ld);                                                         \
    gl_lds16(gs + 64 * ldx, ld + 64 * 64);                                    \
  } while (0)

  f32x4 acc[4][4];
#pragma unroll
  for (int i = 0; i < 4; ++i)
#pragma unroll
    for (int j = 0; j < 4; ++j) acc[i][j] = (f32x4){0.f, 0.f, 0.f, 0.f};

  const int NT = K >> 6;

#pragma unroll
  for (int h = 0; h < 3; ++h) STG(0, h, 0);
#pragma unroll
  for (int h = 0; h < 3; ++h) STG(1, h, 1);
  asm volatile("s_waitcnt vmcnt(6)" ::: "memory");  // tile 0 landed
  bar_raw();

  short8 bfr[4][2];

  for (int t = 0; t < NT; ++t) {
    const int st = t % 3;
    const unsigned short (*LA)[64] = Ls[st][wm >> 1];
    const unsigned short (*LB)[64] = Ls[st][2];
    const int arow0 = (wm & 1) * 64;
    const int brow0 = wn * 64;
    const bool pf = (t + 2 < NT);
    const int s2 = (t + 2) % 3;
#pragma unroll
    for (int p = 0; p < 2; ++p) {
      if (p == 0) {
#pragma unroll
        for (int nj = 0; nj < 4; ++nj)
#pragma unroll
          for (int kk = 0; kk < 2; ++kk)
            bfr[nj][kk] = *(const short8*)
                &LB[brow0 + nj * 16 + r][((kk * 4 + ql) ^ (r & 7)) * 8];
      }
      short8 af[2][2];
#pragma unroll
      for (int im = 0; im < 2; ++im)
#pragma unroll
        for (int kk = 0; kk < 2; ++kk)
          af[im][kk] = *(const short8*)
              &LA[arow0 + (p * 2 + im) * 16 + r][((kk * 4 + ql) ^ (r & 7)) * 8];
      if (pf) {
        if (p == 0) {
          STG(s2, 0, t + 2);
          STG(s2, 1, t + 2);
        } else {
          STG(s2, 2, t + 2);
        }
      }
      bar_raw();
      __builtin_amdgcn_s_setprio(1);
#pragma unroll
      for (int kk = 0; kk < 2; ++kk)
#pragma unroll
        for (int im = 0; im < 2; ++im)
#pragma unroll
          for (int nj = 0; nj < 4; ++nj)
            acc[p * 2 + im][nj] = __builtin_amdgcn_mfma_f32_16x16x32_bf16(
                af[im][kk], bfr[nj][kk], acc[p * 2 + im][nj], 0, 0, 0);
      __builtin_amdgcn_s_setprio(0);
      if (p == 1) {
        if (pf)
          asm volatile("s_waitcnt vmcnt(6)" ::: "memory");
        else if (t + 1 < NT)
          asm volatile("s_waitcnt vmcnt(0)" ::: "memory");
      }
      __builtin_amdgcn_sched_barrier(0);
      bar_raw();
    }
  }
#undef STG

#pragma unroll
  for (int mi = 0; mi < 4; ++mi) {
#pragma unroll
    for (int nj = 0; nj < 4; ++nj) {
#pragma unroll
      for (int rr = 0; rr < 4; ++rr) {
        int mrow = m0 + wm * 64 + mi * 16 + ql * 4 + rr;
        int ncol = n0 + wn * 64 + nj * 16 + r;
        float val = acc[mi][nj][rr];
        if (ADD_BIAS) val += bias[ncol];
        if (OUT_BF16)
          ((unsigned short*)Cptr)[(size_t)mrow * ldC + ncol] = f2bf(val);
        else
          ((float*)Cptr)[(size_t)mrow * ldC + ncol] = val;
      }
    }
  }
}

// ---------------- prep: G-scan + RoPE + phi + scale + transpose + intra-chunk A ----------------
__global__ __launch_bounds__(256)
void k_prep(const unsigned short* __restrict__ qkv, const float* __restrict__ beta,
            unsigned short* __restrict__ Qt, unsigned short* __restrict__ Ktg,
            unsigned short* __restrict__ Ag, float* __restrict__ gch) {
  const int ch = blockIdx.x;
  const int bh = blockIdx.y;
  const int b = bh >> 4, h = bh & 15;
  const int tid = threadIdx.x;
  const int t0 = ch * 64;

  __shared__ float Gs[64];
  __shared__ unsigned short Qs[64][136];
  __shared__ unsigned short Ks[64][136];

  if (tid < 64) {
    float bb = beta[((size_t)(b * 2048 + t0 + tid)) * 16 + h];
#pragma unroll
    for (int off = 1; off < 64; off <<= 1) {
      float o = __shfl_up(bb, off, 64);
      if (tid >= off) bb *= o;
    }
    Gs[tid] = bb;
    if (tid == 63) gch[bh * 32 + ch] = bb;
  }
  __syncthreads();

  const int dgl = tid & 7;
  float invf[8];
#pragma unroll
  for (int j = 0; j < 8; ++j)
    invf[j] = expf((float)(dgl * 8 + j) * -0.14391156831212787f);  // 10000^(-e/64)

  int s = tid >> 3;
#pragma unroll
  for (int rep = 0; rep < 2; ++rep, s += 32) {
    size_t row = ((size_t)(b * 2048 + t0 + s)) * 6144 + (size_t)h * 128;
    short8 qlo = *(const short8*)(qkv + row + dgl * 8);
    short8 qhi = *(const short8*)(qkv + row + 64 + dgl * 8);
    short8 klo = *(const short8*)(qkv + row + 2048 + dgl * 8);
    short8 khi = *(const short8*)(qkv + row + 2048 + 64 + dgl * 8);
    float g = Gs[s];
    float ig = 1.f / g;
    float tg = (float)(t0 + s);
    short8 oql, oqh, okl, okh;
#pragma unroll
    for (int j = 0; j < 8; ++j) {
      float sn, cs;
      __sincosf(tg * invf[j], &sn, &cs);
      float qe = bf2f((unsigned short)qlo[j]), qo = bf2f((unsigned short)qhi[j]);
      float a0 = qe * cs - qo * sn, a1 = qe * sn + qo * cs;
      oql[j] = (short)f2bf(phi_elu1(a0) * g);
      oqh[j] = (short)f2bf(phi_elu1(a1) * g);
      float ke = bf2f((unsigned short)klo[j]), ko = bf2f((unsigned short)khi[j]);
      a0 = ke * cs - ko * sn;
      a1 = ke * sn + ko * cs;
      okl[j] = (short)f2bf(phi_elu1(a0) * ig);
      okh[j] = (short)f2bf(phi_elu1(a1) * ig);
    }
    size_t qbase = (((size_t)bh * 32 + ch) * 64 + s) * 128;
    *(short8*)(Qt + qbase + dgl * 8) = oql;
    *(short8*)(Qt + qbase + 64 + dgl * 8) = oqh;
    *(short8*)&Qs[s][dgl * 8] = oql;
    *(short8*)&Qs[s][64 + dgl * 8] = oqh;
    *(short8*)&Ks[s][dgl * 8] = okl;
    *(short8*)&Ks[s][64 + dgl * 8] = okh;
  }
  __syncthreads();

  {
    const int d = tid >> 1, sh = tid & 1;
    unsigned pk[16];
#pragma unroll
    for (int i = 0; i < 16; ++i)
      pk[i] = (unsigned)Ks[sh * 32 + 2 * i][d] | ((unsigned)Ks[sh * 32 + 2 * i + 1][d] << 16);
    unsigned short* kr = Ktg + ((size_t)bh * 32 + ch) * 8192 + (size_t)d * 64 + sh * 32;
#pragma unroll
    for (int i = 0; i < 4; ++i)
      *(uint4*)(kr + i * 8) = *(uint4*)&pk[i * 4];
  }

  {
    const int lane = tid & 63;
    const int w = tid >> 6;
    const int q = lane >> 4, r = lane & 15;
    f32x4 acc[4];
#pragma unroll
    for (int nt = 0; nt < 4; ++nt) acc[nt] = (f32x4){0.f, 0.f, 0.f, 0.f};
#pragma unroll
    for (int kk = 0; kk < 4; ++kk) {
      short8 af = *(const short8*)&Qs[w * 16 + r][kk * 32 + q * 8];
#pragma unroll
      for (int nt = 0; nt < 4; ++nt) {
        short8 bf = *(const short8*)&Ks[nt * 16 + r][kk * 32 + q * 8];
        acc[nt] = __builtin_amdgcn_mfma_f32_16x16x32_bf16(af, bf, acc[nt], 0, 0, 0);
      }
    }
    unsigned short* Agp = Ag + ((size_t)bh * 32 + ch) * 4096;
#pragma unroll
    for (int nt = 0; nt < 4; ++nt) {
#pragma unroll
      for (int rr = 0; rr < 4; ++rr) {
        int t_l = w * 16 + q * 4 + rr;
        int s_l = nt * 16 + r;
        float val = (s_l <= t_l) ? acc[nt][rr] : 0.f;
        Agp[t_l * 64 + s_l] = f2bf(val);
      }
    }
  }
}

// ---------------- chunk scan, deduplicated: one block per bh ----------------
// grid 32 (bh), 512 threads = 8 waves; wave w owns e-cols [w*16, w*16+16).
// Per chunk: stage Qt/Ktg/Ag/V ONCE; each wave computes its slice's numer
// (Q@S0 + A@V over 4 row-blocks), waves 0-3 compute denom once -> invs[64];
// z updated once; per-wave state update for its 16 cols (S_acc[8]).
__global__ __launch_bounds__(512)
void k_scan(const unsigned short* __restrict__ Qt, const unsigned short* __restrict__ Ktg,
            const unsigned short* __restrict__ Ag, const unsigned short* __restrict__ qkv,
            const float* __restrict__ gch, unsigned short* __restrict__ numerb) {
  const int bh = blockIdx.x;
  const int b = bh >> 4, h = bh & 15;
  const int tid = threadIdx.x;
  const int lane = tid & 63;
  const int w = tid >> 6;        // 0..7: e-slice owner
  const int q = lane >> 4, r = lane & 15;

  __shared__ unsigned short Qs[64][136];        // 17.4KB
  __shared__ unsigned short Kts[128][72];       // 18.4KB
  __shared__ unsigned short As[64][72];         //  9.2KB
  __shared__ unsigned short Vt[128][72];        // 18.4KB  [e][s]
  __shared__ unsigned short SbT[8][16][136];    // 34.8KB  per-wave [e_loc][d]
  __shared__ __align__(16) float zbuf[2][128];  //  1KB
  __shared__ float invs[64];

  f32x4 S_acc[8];   // state cols w*16+r (e), rows ib*16+q*4+rr (d)
#pragma unroll
  for (int i = 0; i < 8; ++i) S_acc[i] = (f32x4){0.f, 0.f, 0.f, 0.f};
  if (tid < 128) zbuf[0][tid] = 0.f;

  for (int ch = 0; ch < 32; ++ch) {
    const int cur = ch & 1, nxt = cur ^ 1;
    __syncthreads();
    // ---- stage (once per chunk) ----
    {
      const unsigned short* Qg = Qt + ((size_t)bh * 32 + ch) * 8192;
#pragma unroll
      for (int i = 0; i < 2; ++i) {
        int c = tid + i * 512;
        int ss = c >> 4, dg = c & 15;
        *(int4*)&Qs[ss][dg * 8] = *(const int4*)(Qg + ss * 128 + dg * 8);
      }
      const unsigned short* Kg = Ktg + ((size_t)bh * 32 + ch) * 8192;
#pragma unroll
      for (int i = 0; i < 2; ++i) {
        int c = tid + i * 512;
        int d = c >> 3, sg = c & 7;
        *(int4*)&Kts[d][sg * 8] = *(const int4*)(Kg + d * 64 + sg * 8);
      }
      const unsigned short* Agp = Ag + ((size_t)bh * 32 + ch) * 4096;
      {
        int t_l = tid >> 3, sg = tid & 7;
        *(int4*)&As[t_l][sg * 8] = *(const int4*)(Agp + t_l * 64 + sg * 8);
      }
      {
        int ss = tid >> 3, ef = tid & 7;
        const unsigned short* vrow =
            qkv + ((size_t)(b * 2048 + ch * 64 + ss)) * 6144 + 4096 + h * 128;
#pragma unroll
        for (int rep = 0; rep < 4; ++rep) {
          int e4 = ef + rep * 8;  // 0..31
          uint2 vv = *(const uint2*)(vrow + e4 * 4);
          const unsigned short* pv = (const unsigned short*)&vv;
#pragma unroll
          for (int j = 0; j < 4; ++j) Vt[e4 * 4 + j][ss] = pv[j];
        }
      }
      // state readout: wave w's S (cols w*16+r) -> SbT[w][r][d]
#pragma unroll
      for (int ib = 0; ib < 8; ++ib) {
        uint2 pk;
        pk.x = (unsigned)f2bf(S_acc[ib][0]) | ((unsigned)f2bf(S_acc[ib][1]) << 16);
        pk.y = (unsigned)f2bf(S_acc[ib][2]) | ((unsigned)f2bf(S_acc[ib][3]) << 16);
        *(uint2*)&SbT[w][r][ib * 16 + q * 4] = pk;
      }
    }
    __syncthreads();

    const float gc = gch[bh * 32 + ch];

    // ---- numer: rows wb*16+q*4+rr, col w*16+r ----
    f32x4 nacc[4];
#pragma unroll
    for (int wb = 0; wb < 4; ++wb) nacc[wb] = (f32x4){0.f, 0.f, 0.f, 0.f};
#pragma unroll
    for (int kk = 0; kk < 4; ++kk) {
      short8 sb = *(const short8*)&SbT[w][r][kk * 32 + q * 8];
#pragma unroll
      for (int wb = 0; wb < 4; ++wb) {
        short8 aq = *(const short8*)&Qs[wb * 16 + r][kk * 32 + q * 8];
        nacc[wb] = __builtin_amdgcn_mfma_f32_16x16x32_bf16(aq, sb, nacc[wb], 0, 0, 0);
      }
    }
    short8 vf[2];
#pragma unroll
    for (int kk = 0; kk < 2; ++kk) {
      vf[kk] = *(const short8*)&Vt[w * 16 + r][kk * 32 + q * 8];
#pragma unroll
      for (int wb = 0; wb < 4; ++wb) {
        short8 aa = *(const short8*)&As[wb * 16 + r][kk * 32 + q * 8];
        nacc[wb] = __builtin_amdgcn_mfma_f32_16x16x32_bf16(aa, vf[kk], nacc[wb], 0, 0, 0);
      }
    }

    // ---- denom (once): waves 0-3 cover rows w*16+r ----
    if (w < 4) {
      float dsum = 0.f;
#pragma unroll
      for (int kk = 0; kk < 4; ++kk) {
        short8 aq = *(const short8*)&Qs[w * 16 + r][kk * 32 + q * 8];
        const float* zp = &zbuf[cur][kk * 32 + q * 8];
        float4 z0a = *(const float4*)zp;
        float4 z0b = *(const float4*)(zp + 4);
        dsum = fmaf(bf2f((unsigned short)aq[0]), z0a.x, dsum);
        dsum = fmaf(bf2f((unsigned short)aq[1]), z0a.y, dsum);
        dsum = fmaf(bf2f((unsigned short)aq[2]), z0a.z, dsum);
        dsum = fmaf(bf2f((unsigned short)aq[3]), z0a.w, dsum);
        dsum = fmaf(bf2f((unsigned short)aq[4]), z0b.x, dsum);
        dsum = fmaf(bf2f((unsigned short)aq[5]), z0b.y, dsum);
        dsum = fmaf(bf2f((unsigned short)aq[6]), z0b.z, dsum);
        dsum = fmaf(bf2f((unsigned short)aq[7]), z0b.w, dsum);
      }
#pragma unroll
      for (int kk = 0; kk < 2; ++kk) {
        short8 aa = *(const short8*)&As[w * 16 + r][kk * 32 + q * 8];
#pragma unroll
        for (int j = 0; j < 8; ++j) dsum += bf2f((unsigned short)aa[j]);
      }
      dsum += __shfl_xor(dsum, 16, 64);
      dsum += __shfl_xor(dsum, 32, 64);
      if (lane < 16) invs[w * 16 + lane] = 1.f / (dsum + 1e-6f);
    }

    // ---- z update (once): d = tid>>2, quarter = tid&3 ----
    {
      int d = tid >> 2, qt = tid & 3;
      const unsigned short* kp = &Kts[d][qt * 16];
      float zs = 0.f;
#pragma unroll
      for (int i = 0; i < 2; ++i) {
        short8 kv = *(const short8*)(kp + i * 8);
#pragma unroll
        for (int j = 0; j < 8; ++j) zs += bf2f((unsigned short)kv[j]);
      }
      zs += __shfl_xor(zs, 1, 64);
      zs += __shfl_xor(zs, 2, 64);
      if (qt == 0) zbuf[nxt][d] = gc * (zbuf[cur][d] + zs);
    }

    // ---- state update: S = gc * (S0 + Kt^T V), cols w*16+r ----
#pragma unroll
    for (int ib = 0; ib < 8; ++ib) {
#pragma unroll
      for (int kk = 0; kk < 2; ++kk) {
        short8 ak = *(const short8*)&Kts[ib * 16 + r][kk * 32 + q * 8];
        S_acc[ib] = __builtin_amdgcn_mfma_f32_16x16x32_bf16(ak, vf[kk], S_acc[ib], 0, 0, 0);
      }
#pragma unroll
      for (int rr = 0; rr < 4; ++rr) S_acc[ib][rr] *= gc;
    }

    __syncthreads();  // invs ready

    // ---- scale + store numer ----
#pragma unroll
    for (int wb = 0; wb < 4; ++wb) {
#pragma unroll
      for (int rr = 0; rr < 4; ++rr) {
        int t_l = wb * 16 + q * 4 + rr;
        float inv_r = invs[t_l];
        size_t m = (size_t)b * 2048 + ch * 64 + t_l;
        numerb[m * 2048 + h * 128 + w * 16 + r] = f2bf(nacc[wb][rr] * inv_r);
      }
    }
  }
}

extern "C" void kernel_launch(void* const* d_in, const int* in_sizes, int n_in,
                              void* d_out, int out_size, void* d_ws, size_t ws_size,
                              hipStream_t stream) {
  const float* x  = (const float*)d_in[0];
  const float* Wq = (const float*)d_in[1];
  const float* Wk = (const float*)d_in[2];
  const float* Wv = (const float*)d_in[3];
  const float* Wg = (const float*)d_in[4];
  const float* bg = (const float*)d_in[5];
  const float* Wo = (const float*)d_in[6];
  const float* bo = (const float*)d_in[7];

  // workspace layout (bytes), total 134,742,016 (unchanged)
  char* ws = (char*)d_ws;
  unsigned short* xb    = (unsigned short*)(ws);             // 16.7MB: xb -> Qt
  unsigned short* Qt    = (unsigned short*)(ws);
  unsigned short* Wt    = (unsigned short*)(ws + 16777216);  // 25.2MB: Wt -> Ktg+Ag
  unsigned short* Ktg   = (unsigned short*)(ws + 16777216);
  unsigned short* Ag    = (unsigned short*)(ws + 33554432);
  unsigned short* Wot   = (unsigned short*)(ws + 41943040);  //  8.4MB
  unsigned short* qkvb  = (unsigned short*)(ws + 50331648);  // 50.3MB
  float*          beta  = (float*)(ws + 100663296);          //  0.26MB
  unsigned short* Wgt16 = (unsigned short*)(ws + 101187584); // 64KB (dead after betaW)
  unsigned short* numerb= (unsigned short*)(ws + 101187584); // 16.8MB bf16 (from scan on)
  // gchunk [32 bh][32 ch] fp32 = 4KB at head of d_out (fully overwritten by
  // the final out-projection GEMM afterwards).
  float*          gch   = (float*)d_out;

  k_cast<<<8192, 256, 0, stream>>>(x, xb);
  k_transw<<<dim3(32, 32, 5), 256, 0, stream>>>(Wq, Wk, Wv, Wo, Wg, Wt, Wot, Wgt16);
  k_gemm<true, false><<<dim3(48, 32), 256, 0, stream>>>(
      xb, Wt, qkvb, nullptr, 4096, 6144, 2048, 2048, 6144);
  k_betaW<<<1024, 256, 0, stream>>>(xb, Wgt16, bg, beta);
  k_prep<<<dim3(32, 32), 256, 0, stream>>>(qkvb, beta, Qt, Ktg, Ag, gch);
  k_scan<<<32, 512, 0, stream>>>(Qt, Ktg, Ag, qkvb, gch, numerb);
  // out-proj: M=4096, N=2048 -> grid 16 x 16 = 256 blocks = 1 exact round.
  k_gemm2<false, true><<<dim3(16, 16), 512, 0, stream>>>(
      numerb, Wot, d_out, bo, 4096, 2048, 2048, 2048, 2048);
}

// Round 7
// 406.954 us; speedup vs baseline: 1.1544x; 1.1544x over previous
//
#include <hip/hip_runtime.h>

// DeltaNet fused pipeline, round 12 (= round 11 resubmitted verbatim; the
// round-11 bench never executed — container acquisition failed twice):
//   k_cast:    x fp32 -> bf16
//   k_transw:  Wq/Wk/Wv -> Wt (N x K bf16), Wo -> Wot, Wg -> Wgt16 (z==4)
//   k_gemm:    bf16 MFMA 128x128 GEMM (proven, ~117us QKV)
//   k_betaW:   wave-per-row dot: beta = clip(sigmoid(xb . Wgt16[h] + bg))
//   k_prep:    G-scan + RoPE + phi + scale + K^T transpose + intra-chunk A
//              + V transpose pack Vg[bh][ch][e][s]
//   --- two-level chunk scan (replaces serial k_scan, was ~220us) ---
//   k_kv:      per (bh,ch): M_c = (K_c^T V_c)^T stored [e][d] bf16 into Mg;
//              mz[d] = rowsum_s Kt. Fully parallel (1024 blocks).
//              FIX(r11): LDS staging 4 iterations (was 2 -> half-filled LDS).
//   k_sprefix: per element slice: serial 32-chunk fp32 register prefix
//              S_before(c) = g_{c-1}(S_before(c-1)+M_{c-1}), IN PLACE over
//              Mg. Same for z over mz. 256 blocks, element-parallel.
//   k_out:     per (bh,ch): numer = Q@S_c + A@V, denom = rowsum(A)+Q.z_c.
//              FIX(r11): Qs 4 iters (was 2), As 2 (was 1), Vs 4 (was 2).
//   k_gemm2:   256x128 triple-buffered GEMM (out-proj; 256 blocks)
//
// workspace layout (134,742,016 B):
//   0         xb (16.8M)  [dead after betaW] -> Qt (prep->out)
//   16777216  Wt (25.2M)  [dead after QKV gemm] -> Ktg(16.8M)+Ag(8.4M)
//   41943040  Wot (8.4M)  [til final gemm]
//   50331648  qkvb (50.3M)[dead after prep] -> Mg/Sg bf16 33.5M
//   83886080  mz/zg fp32 0.5M (kv->sprefix->out)
//   100663296 numerb (16.8M) (out->final gemm)
//   117440512 Vg (16.8M) (prep->kv,out)
//   134217728 beta (0.26M) (betaW->prep)
//   134479872 Wgt16 (64K) (transw->betaW)

typedef __attribute__((ext_vector_type(8))) short short8;
typedef __attribute__((ext_vector_type(4))) float f32x4;

__device__ __forceinline__ unsigned short f2bf(float f) {
  unsigned u = __float_as_uint(f);
  u += 0x7fffu + ((u >> 16) & 1u);   // RNE
  return (unsigned short)(u >> 16);
}
__device__ __forceinline__ float bf2f(unsigned short s) {
  return __uint_as_float(((unsigned)s) << 16);
}
__device__ __forceinline__ float phi_elu1(float x) {
  return x > 0.f ? x + 1.f : expf(x);
}
__device__ __forceinline__ void gl_lds16(const void* g, void* l) {
  __builtin_amdgcn_global_load_lds(
      (const __attribute__((address_space(1))) void*)g,
      (__attribute__((address_space(3))) void*)l, 16, 0, 0);
}
__device__ __forceinline__ void bar_raw() {
  asm volatile("" ::: "memory");
  __builtin_amdgcn_s_barrier();
  asm volatile("" ::: "memory");
}

// ---------------- cast x -> bf16 ----------------
__global__ __launch_bounds__(256)
void k_cast(const float* __restrict__ x, unsigned short* __restrict__ xb) {
  int i = (blockIdx.x * 256 + threadIdx.x) * 4;
  float4 f = *(const float4*)(x + i);
  uint2 p;
  p.x = (unsigned)f2bf(f.x) | ((unsigned)f2bf(f.y) << 16);
  p.y = (unsigned)f2bf(f.z) | ((unsigned)f2bf(f.w) << 16);
  *(uint2*)(xb + i) = p;
}

// ---------------- transpose+cast weights ----------------
__global__ __launch_bounds__(256)
void k_transw(const float* __restrict__ Wq, const float* __restrict__ Wk,
              const float* __restrict__ Wv, const float* __restrict__ Wo,
              const float* __restrict__ Wg,
              unsigned short* __restrict__ Wt, unsigned short* __restrict__ Wot,
              unsigned short* __restrict__ Wgt16) {
  const int z = blockIdx.z;
  if (z == 4) {
    if (blockIdx.y != 0) return;
    int idx = blockIdx.x * 256 + threadIdx.x;  // 8192 threads
    int h = idx >> 9, k4 = (idx & 511) * 4;
    uint2 p;
    p.x = (unsigned)f2bf(Wg[(k4 + 0) * 16 + h]) | ((unsigned)f2bf(Wg[(k4 + 1) * 16 + h]) << 16);
    p.y = (unsigned)f2bf(Wg[(k4 + 2) * 16 + h]) | ((unsigned)f2bf(Wg[(k4 + 3) * 16 + h]) << 16);
    *(uint2*)(Wgt16 + (size_t)h * 2048 + k4) = p;
    return;
  }
  const float* W = (z == 0) ? Wq : (z == 1) ? Wk : (z == 2) ? Wv : Wo;
  unsigned short* out = (z < 3) ? (Wt + (size_t)z * 2048 * 2048) : Wot;
  __shared__ float tile[64][65];
  const int n0 = blockIdx.x * 64;
  const int k0 = blockIdx.y * 64;
  const int tx = threadIdx.x & 63;
  const int ty = threadIdx.x >> 6;
#pragma unroll
  for (int rl = 0; rl < 16; ++rl) {
    int kk = rl * 4 + ty;
    tile[kk][tx] = W[(size_t)(k0 + kk) * 2048 + n0 + tx];
  }
  __syncthreads();
#pragma unroll
  for (int rl = 0; rl < 16; ++rl) {
    int nn = rl * 4 + ty;
    out[(size_t)(n0 + nn) * 2048 + k0 + tx] = f2bf(tile[tx][nn]);
  }
}

// ---------------- beta ----------------
__global__ __launch_bounds__(256)
void k_betaW(const unsigned short* __restrict__ xb, const unsigned short* __restrict__ Wgt16,
             const float* __restrict__ bg, float* __restrict__ beta) {
  const int w = threadIdx.x >> 6;
  const int lane = threadIdx.x & 63;
  const int m = blockIdx.x * 4 + w;
  const int h = lane & 15, kq = lane >> 4;
  const unsigned short* xr = xb + (size_t)m * 2048 + kq * 512;
  const unsigned short* wr = Wgt16 + (size_t)h * 2048 + kq * 512;
  float acc = 0.f;
#pragma unroll 8
  for (int i = 0; i < 64; ++i) {
    short8 xv = *(const short8*)(xr + i * 8);
    short8 wv = *(const short8*)(wr + i * 8);
#pragma unroll
    for (int j = 0; j < 8; ++j)
      acc = fmaf(bf2f((unsigned short)xv[j]), bf2f((unsigned short)wv[j]), acc);
  }
  acc += __shfl_xor(acc, 16, 64);
  acc += __shfl_xor(acc, 32, 64);
  if (lane < 16) {
    float v = acc + bg[h];
    float bv = 1.f / (1.f + expf(-v));
    beta[(size_t)m * 16 + h] = fminf(fmaxf(bv, 0.8f), 0.9995f);
  }
}

// ---------------- bf16 MFMA GEMM 128x128 (QKV) ----------------
template <bool OUT_BF16, bool ADD_BIAS>
__global__ __launch_bounds__(256)
void k_gemm(const unsigned short* __restrict__ A, const unsigned short* __restrict__ Bt,
            void* __restrict__ Cptr, const float* __restrict__ bias,
            int M, int N, int K, int ldA, int ldC) {
  __shared__ __align__(16) unsigned short As[128][64];
  __shared__ __align__(16) unsigned short Bs[128][64];
  const int tid = threadIdx.x;
  const int n0 = blockIdx.x * 128;
  const int m0 = blockIdx.y * 128;
  const int lane = tid & 63;
  const int w = tid >> 6;
  const int wm = w >> 1, wn = w & 1;
  const int q = lane >> 4, r = lane & 15;

  const int srow0 = w * 8 + (lane >> 3);
  const int scol = ((lane & 7) ^ ((lane >> 3) & 7)) * 8;

  f32x4 acc[4][4];
#pragma unroll
  for (int i = 0; i < 4; ++i)
#pragma unroll
    for (int j = 0; j < 4; ++j) acc[i][j] = (f32x4){0.f, 0.f, 0.f, 0.f};

  const unsigned short* A0 = A + (size_t)(m0 + srow0) * ldA + scol;
  const unsigned short* B0 = Bt + (size_t)(n0 + srow0) * K + scol;
  unsigned short* lA = &As[srow0][(lane & 7) * 8];
  unsigned short* lB = &Bs[srow0][(lane & 7) * 8];

  const int rsw = r & 7;

  for (int kt = 0; kt < K; kt += 64) {
    __syncthreads();
#pragma unroll
    for (int i = 0; i < 4; ++i) {
      gl_lds16(A0 + (size_t)i * 32 * ldA + kt, lA + i * 2048);
      gl_lds16(B0 + (size_t)i * 32 * K + kt, lB + i * 2048);
    }
    __syncthreads();
#pragma unroll
    for (int kk = 0; kk < 2; ++kk) {
      const int ps = ((kk * 4 + q) ^ rsw) * 8;
      short8 af[4], bfr[4];
#pragma unroll
      for (int i = 0; i < 4; ++i)
        af[i] = *(const short8*)&As[wm * 64 + i * 16 + r][ps];
#pragma unroll
      for (int j = 0; j < 4; ++j)
        bfr[j] = *(const short8*)&Bs[wn * 64 + j * 16 + r][ps];
#pragma unroll
      for (int i = 0; i < 4; ++i)
#pragma unroll
        for (int j = 0; j < 4; ++j)
          acc[i][j] = __builtin_amdgcn_mfma_f32_16x16x32_bf16(af[i], bfr[j], acc[i][j], 0, 0, 0);
    }
  }
#pragma unroll
  for (int i = 0; i < 4; ++i) {
#pragma unroll
    for (int j = 0; j < 4; ++j) {
#pragma unroll
      for (int rr = 0; rr < 4; ++rr) {
        int mi = m0 + wm * 64 + i * 16 + q * 4 + rr;
        int ni = n0 + wn * 64 + j * 16 + r;
        float val = acc[i][j][rr];
        if (ADD_BIAS) val += bias[ni];
        if (OUT_BF16)
          ((unsigned short*)Cptr)[(size_t)mi * ldC + ni] = f2bf(val);
        else
          ((float*)Cptr)[(size_t)mi * ldC + ni] = val;
      }
    }
  }
}

// ---------------- bf16 MFMA GEMM 256x128, triple-buffered (out-proj) ----------------
template <bool OUT_BF16, bool ADD_BIAS>
__global__ __launch_bounds__(512, 2)
void k_gemm2(const unsigned short* __restrict__ A, const unsigned short* __restrict__ Bt,
             void* __restrict__ Cptr, const float* __restrict__ bias,
             int M, int N, int K, int ldA, int ldC) {
  __shared__ __align__(16) unsigned short Ls[3][3][128][64];  // 144KB
  const int tid = threadIdx.x;
  const int lane = tid & 63;
  const int w = tid >> 6;
  const int wm = w >> 1;
  const int wn = w & 1;
  const int ql = lane >> 4;
  const int r = lane & 15;

  const int nwg = gridDim.x * gridDim.y;
  const int orig = blockIdx.y * gridDim.x + blockIdx.x;
  const int li = (orig & 7) * (nwg >> 3) + (orig >> 3);
  const int m0 = (li & 15) * 256;
  const int n0 = (li >> 4) * 128;

  const int srow = tid >> 3;
  const int sphys = tid & 7;
  const int slog = sphys ^ (srow & 7);
  const unsigned short* Ab = A + (size_t)(m0 + srow) * ldA + slog * 8;
  const unsigned short* Bb = Bt + (size_t)(n0 + srow) * K + slog * 8;

#define STG(st, h, tt)                                                        \
  do {                                                                        \
    const size_t ldx = ((h) == 2) ? (size_t)K : (size_t)ldA;                  \
    const unsigned short* gs =                                                \
        (((h) == 2) ? Bb : (Ab + (size_t)((h) * 128) * ldA)) +                \
        (size_t)(tt) * 64;                                                    \
    unsigned short* ld = &Ls[(st)][(h)][srow][sphys * 8];                     \
    gl_lds16(gs, ld);                                                         \
    gl_lds16(gs + 64 * ldx, ld + 64 * 64);                                    \
  } while (0)

  f32x4 acc[4][4];
#pragma unroll
  for (int i = 0; i < 4; ++i)
#pragma unroll
    for (int j = 0; j < 4; ++j) acc[i][j] = (f32x4){0.f, 0.f, 0.f, 0.f};

  const int NT = K >> 6;

#pragma unroll
  for (int h = 0; h < 3; ++h) STG(0, h, 0);
#pragma unroll
  for (int h = 0; h < 3; ++h) STG(1, h, 1);
  asm volatile("s_waitcnt vmcnt(6)" ::: "memory");
  bar_raw();

  short8 bfr[4][2];

  for (int t = 0; t < NT; ++t) {
    const int st = t % 3;
    const unsigned short (*LA)[64] = Ls[st][wm >> 1];
    const unsigned short (*LB)[64] = Ls[st][2];
    const int arow0 = (wm & 1) * 64;
    const int brow0 = wn * 64;
    const bool pf = (t + 2 < NT);
    const int s2 = (t + 2) % 3;
#pragma unroll
    for (int p = 0; p < 2; ++p) {
      if (p == 0) {
#pragma unroll
        for (int nj = 0; nj < 4; ++nj)
#pragma unroll
          for (int kk = 0; kk < 2; ++kk)
            bfr[nj][kk] = *(const short8*)
                &LB[brow0 + nj * 16 + r][((kk * 4 + ql) ^ (r & 7)) * 8];
      }
      short8 af[2][2];
#pragma unroll
      for (int im = 0; im < 2; ++im)
#pragma unroll
        for (int kk = 0; kk < 2; ++kk)
          af[im][kk] = *(const short8*)
              &LA[arow0 + (p * 2 + im) * 16 + r][((kk * 4 + ql) ^ (r & 7)) * 8];
      if (pf) {
        if (p == 0) {
          STG(s2, 0, t + 2);
          STG(s2, 1, t + 2);
        } else {
          STG(s2, 2, t + 2);
        }
      }
      bar_raw();
      __builtin_amdgcn_s_setprio(1);
#pragma unroll
      for (int kk = 0; kk < 2; ++kk)
#pragma unroll
        for (int im = 0; im < 2; ++im)
#pragma unroll
          for (int nj = 0; nj < 4; ++nj)
            acc[p * 2 + im][nj] = __builtin_amdgcn_mfma_f32_16x16x32_bf16(
                af[im][kk], bfr[nj][kk], acc[p * 2 + im][nj], 0, 0, 0);
      __builtin_amdgcn_s_setprio(0);
      if (p == 1) {
        if (pf)
          asm volatile("s_waitcnt vmcnt(6)" ::: "memory");
        else if (t + 1 < NT)
          asm volatile("s_waitcnt vmcnt(0)" ::: "memory");
      }
      __builtin_amdgcn_sched_barrier(0);
      bar_raw();
    }
  }
#undef STG

#pragma unroll
  for (int mi = 0; mi < 4; ++mi) {
#pragma unroll
    for (int nj = 0; nj < 4; ++nj) {
#pragma unroll
      for (int rr = 0; rr < 4; ++rr) {
        int mrow = m0 + wm * 64 + mi * 16 + ql * 4 + rr;
        int ncol = n0 + wn * 64 + nj * 16 + r;
        float val = acc[mi][nj][rr];
        if (ADD_BIAS) val += bias[ncol];
        if (OUT_BF16)
          ((unsigned short*)Cptr)[(size_t)mrow * ldC + ncol] = f2bf(val);
        else
          ((float*)Cptr)[(size_t)mrow * ldC + ncol] = val;
      }
    }
  }
}

// ---------------- prep: G-scan + RoPE + phi + scale + K^T + A + V-pack ----------------
__global__ __launch_bounds__(256)
void k_prep(const unsigned short* __restrict__ qkv, const float* __restrict__ beta,
            unsigned short* __restrict__ Qt, unsigned short* __restrict__ Ktg,
            unsigned short* __restrict__ Ag, unsigned short* __restrict__ Vg,
            float* __restrict__ gch) {
  const int ch = blockIdx.x;
  const int bh = blockIdx.y;
  const int b = bh >> 4, h = bh & 15;
  const int tid = threadIdx.x;
  const int t0 = ch * 64;

  __shared__ float Gs[64];
  __shared__ unsigned short Qs[64][136];
  __shared__ unsigned short Ks[64][136];
  __shared__ unsigned short Vs[128][72];  // [e][s]

  if (tid < 64) {
    float bb = beta[((size_t)(b * 2048 + t0 + tid)) * 16 + h];
#pragma unroll
    for (int off = 1; off < 64; off <<= 1) {
      float o = __shfl_up(bb, off, 64);
      if (tid >= off) bb *= o;
    }
    Gs[tid] = bb;
    if (tid == 63) gch[bh * 32 + ch] = bb;
  }
  __syncthreads();

  const int dgl = tid & 7;
  float invf[8];
#pragma unroll
  for (int j = 0; j < 8; ++j)
    invf[j] = expf((float)(dgl * 8 + j) * -0.14391156831212787f);  // 10000^(-e/64)

  int s = tid >> 3;
#pragma unroll
  for (int rep = 0; rep < 2; ++rep, s += 32) {
    size_t row = ((size_t)(b * 2048 + t0 + s)) * 6144 + (size_t)h * 128;
    short8 qlo = *(const short8*)(qkv + row + dgl * 8);
    short8 qhi = *(const short8*)(qkv + row + 64 + dgl * 8);
    short8 klo = *(const short8*)(qkv + row + 2048 + dgl * 8);
    short8 khi = *(const short8*)(qkv + row + 2048 + 64 + dgl * 8);
    float g = Gs[s];
    float ig = 1.f / g;
    float tg = (float)(t0 + s);
    short8 oql, oqh, okl, okh;
#pragma unroll
    for (int j = 0; j < 8; ++j) {
      float sn, cs;
      __sincosf(tg * invf[j], &sn, &cs);
      float qe = bf2f((unsigned short)qlo[j]), qo = bf2f((unsigned short)qhi[j]);
      float a0 = qe * cs - qo * sn, a1 = qe * sn + qo * cs;
      oql[j] = (short)f2bf(phi_elu1(a0) * g);
      oqh[j] = (short)f2bf(phi_elu1(a1) * g);
      float ke = bf2f((unsigned short)klo[j]), ko = bf2f((unsigned short)khi[j]);
      a0 = ke * cs - ko * sn;
      a1 = ke * sn + ko * cs;
      okl[j] = (short)f2bf(phi_elu1(a0) * ig);
      okh[j] = (short)f2bf(phi_elu1(a1) * ig);
    }
    size_t qbase = (((size_t)bh * 32 + ch) * 64 + s) * 128;
    *(short8*)(Qt + qbase + dgl * 8) = oql;
    *(short8*)(Qt + qbase + 64 + dgl * 8) = oqh;
    *(short8*)&Qs[s][dgl * 8] = oql;
    *(short8*)&Qs[s][64 + dgl * 8] = oqh;
    *(short8*)&Ks[s][dgl * 8] = okl;
    *(short8*)&Ks[s][64 + dgl * 8] = okh;
  }
  // V transpose scatter: thread handles row s2, 32 e-values
  {
    const int s2 = tid >> 2, qe = tid & 3;
    const unsigned short* vrow =
        qkv + ((size_t)(b * 2048 + t0 + s2)) * 6144 + 4096 + (size_t)h * 128 + qe * 32;
#pragma unroll
    for (int i = 0; i < 4; ++i) {
      short8 vv = *(const short8*)(vrow + i * 8);
#pragma unroll
      for (int j = 0; j < 8; ++j) Vs[qe * 32 + i * 8 + j][s2] = (unsigned short)vv[j];
    }
  }
  __syncthreads();

  {
    const int d = tid >> 1, sh = tid & 1;
    unsigned pk[16];
#pragma unroll
    for (int i = 0; i < 16; ++i)
      pk[i] = (unsigned)Ks[sh * 32 + 2 * i][d] | ((unsigned)Ks[sh * 32 + 2 * i + 1][d] << 16);
    unsigned short* kr = Ktg + ((size_t)bh * 32 + ch) * 8192 + (size_t)d * 64 + sh * 32;
#pragma unroll
    for (int i = 0; i < 4; ++i)
      *(uint4*)(kr + i * 8) = *(uint4*)&pk[i * 4];
    // Vg write: [e][s] packed
    unsigned short* vr = Vg + ((size_t)bh * 32 + ch) * 8192 + (size_t)d * 64 + sh * 32;
#pragma unroll
    for (int i = 0; i < 4; ++i)
      *(uint4*)(vr + i * 8) = *(const uint4*)&Vs[d][sh * 32 + i * 8];
  }

  {
    const int lane = tid & 63;
    const int w = tid >> 6;
    const int q = lane >> 4, r = lane & 15;
    f32x4 acc[4];
#pragma unroll
    for (int nt = 0; nt < 4; ++nt) acc[nt] = (f32x4){0.f, 0.f, 0.f, 0.f};
#pragma unroll
    for (int kk = 0; kk < 4; ++kk) {
      short8 af = *(const short8*)&Qs[w * 16 + r][kk * 32 + q * 8];
#pragma unroll
      for (int nt = 0; nt < 4; ++nt) {
        short8 bf = *(const short8*)&Ks[nt * 16 + r][kk * 32 + q * 8];
        acc[nt] = __builtin_amdgcn_mfma_f32_16x16x32_bf16(af, bf, acc[nt], 0, 0, 0);
      }
    }
    unsigned short* Agp = Ag + ((size_t)bh * 32 + ch) * 4096;
#pragma unroll
    for (int nt = 0; nt < 4; ++nt) {
#pragma unroll
      for (int rr = 0; rr < 4; ++rr) {
        int t_l = w * 16 + q * 4 + rr;
        int s_l = nt * 16 + r;
        float val = (s_l <= t_l) ? acc[nt][rr] : 0.f;
        Agp[t_l * 64 + s_l] = f2bf(val);
      }
    }
  }
}

// ---------------- k_kv: M_c = (K^T V)^T  [e][d] bf16; mz[d] ----------------
__global__ __launch_bounds__(256)
void k_kv(const unsigned short* __restrict__ Ktg, const unsigned short* __restrict__ Vg,
          unsigned short* __restrict__ Mg, float* __restrict__ mzg) {
  const int ch = blockIdx.x, bh = blockIdx.y;
  const int tid = threadIdx.x, lane = tid & 63, w = tid >> 6;
  const int q = lane >> 4, r = lane & 15;
  __shared__ unsigned short Kts[128][72];
  __shared__ unsigned short Vs[128][72];
  const unsigned short* Kp = Ktg + ((size_t)bh * 32 + ch) * 8192;
  const unsigned short* Vp = Vg + ((size_t)bh * 32 + ch) * 8192;
#pragma unroll
  for (int i = 0; i < 4; ++i) {   // 4 iters: full 128x64 each
    int c = tid + i * 256;
    int dd = c >> 3, sg = c & 7;
    *(int4*)&Kts[dd][sg * 8] = *(const int4*)(Kp + dd * 64 + sg * 8);
    *(int4*)&Vs[dd][sg * 8] = *(const int4*)(Vp + dd * 64 + sg * 8);
  }
  __syncthreads();
  f32x4 acc[2][8];
#pragma unroll
  for (int jj = 0; jj < 2; ++jj)
#pragma unroll
    for (int i = 0; i < 8; ++i) acc[jj][i] = (f32x4){0.f, 0.f, 0.f, 0.f};
#pragma unroll
  for (int kk = 0; kk < 2; ++kk) {
    short8 af[2];
    af[0] = *(const short8*)&Vs[(w * 2 + 0) * 16 + r][kk * 32 + q * 8];
    af[1] = *(const short8*)&Vs[(w * 2 + 1) * 16 + r][kk * 32 + q * 8];
#pragma unroll
    for (int i = 0; i < 8; ++i) {
      short8 bf = *(const short8*)&Kts[i * 16 + r][kk * 32 + q * 8];
      acc[0][i] = __builtin_amdgcn_mfma_f32_16x16x32_bf16(af[0], bf, acc[0][i], 0, 0, 0);
      acc[1][i] = __builtin_amdgcn_mfma_f32_16x16x32_bf16(af[1], bf, acc[1][i], 0, 0, 0);
    }
  }
  // mz[d] = rowsum_s Kts[d][s]
  {
    int dd = tid >> 1, sh = tid & 1;
    const unsigned short* kp = &Kts[dd][sh * 32];
    float zs = 0.f;
#pragma unroll
    for (int i = 0; i < 4; ++i) {
      short8 kv = *(const short8*)(kp + i * 8);
#pragma unroll
      for (int j = 0; j < 8; ++j) zs += bf2f((unsigned short)kv[j]);
    }
    zs += __shfl_xor(zs, 1, 64);
    if (sh == 0) mzg[((size_t)bh * 32 + ch) * 128 + dd] = zs;
  }
  unsigned short* Mp = Mg + ((size_t)bh * 32 + ch) * 16384;
#pragma unroll
  for (int jj = 0; jj < 2; ++jj)
#pragma unroll
    for (int i = 0; i < 8; ++i)
#pragma unroll
      for (int rr = 0; rr < 4; ++rr) {
        int e = (w * 2 + jj) * 16 + q * 4 + rr;
        Mp[e * 128 + i * 16 + r] = f2bf(acc[jj][i][rr]);
      }
}

// ---------------- k_sprefix: in-place weighted prefix over Mg (and mz) -------
// grid (8 esplit, 32 bh), 256 thr. Thread owns 8 contiguous d of one e-row.
// S_before(c) = g_{c-1} (S_before(c-1) + M_{c-1}); write BEFORE update.
__global__ __launch_bounds__(256)
void k_sprefix(unsigned short* __restrict__ Msg, float* __restrict__ mzg,
               const float* __restrict__ gch) {
  const int es = blockIdx.x;
  const int bh = blockIdx.y;
  const int tid = threadIdx.x;
  const int e = es * 16 + (tid >> 4);
  const int d0 = (tid & 15) * 8;
  unsigned short* base = Msg + (size_t)bh * 32 * 16384 + (size_t)e * 128 + d0;
  const float* gp = gch + bh * 32;
  float sv[8];
#pragma unroll
  for (int i = 0; i < 8; ++i) sv[i] = 0.f;
  uint4 mcur = *(const uint4*)base;
  for (int c = 0; c < 32; ++c) {
    uint4 mnext;
    if (c < 31) mnext = *(const uint4*)(base + (size_t)(c + 1) * 16384);
    uint4 so;
    so.x = (unsigned)f2bf(sv[0]) | ((unsigned)f2bf(sv[1]) << 16);
    so.y = (unsigned)f2bf(sv[2]) | ((unsigned)f2bf(sv[3]) << 16);
    so.z = (unsigned)f2bf(sv[4]) | ((unsigned)f2bf(sv[5]) << 16);
    so.w = (unsigned)f2bf(sv[6]) | ((unsigned)f2bf(sv[7]) << 16);
    *(uint4*)(base + (size_t)c * 16384) = so;
    float g = gp[c];
    const unsigned short* mp = (const unsigned short*)&mcur;
#pragma unroll
    for (int i = 0; i < 8; ++i) sv[i] = g * (sv[i] + bf2f(mp[i]));
    mcur = mnext;
  }
  if (es == 0 && tid < 128) {
    float* zb = mzg + (size_t)bh * 32 * 128 + tid;
    float z = 0.f;
    float zc = zb[0];
    for (int c = 0; c < 32; ++c) {
      float znext = (c < 31) ? zb[(size_t)(c + 1) * 128] : 0.f;
      zb[(size_t)c * 128] = z;
      z = gp[c] * (z + zc);
      zc = znext;
    }
  }
}

// ---------------- k_out: numer = Q@S + A@V; denom = rowsum(A)+Q.z ----------
__global__ __launch_bounds__(256)
void k_out(const unsigned short* __restrict__ Qt, const unsigned short* __restrict__ Sg,
           const unsigned short* __restrict__ Ag, const unsigned short* __restrict__ Vg,
           const float* __restrict__ zg, unsigned short* __restrict__ numerb) {
  const int ch = blockIdx.x, bh = blockIdx.y;
  const int b = bh >> 4, h = bh & 15;
  const int tid = threadIdx.x, lane = tid & 63, w = tid >> 6;
  const int q = lane >> 4, r = lane & 15;
  __shared__ unsigned short Qs[64][136];
  __shared__ unsigned short Ss[128][136];  // [e][d]
  __shared__ unsigned short As[64][72];
  __shared__ unsigned short Vs[128][72];   // [e][s]
  __shared__ float zc[128];
  __shared__ float invs[64];

  const unsigned short* Qg = Qt + ((size_t)bh * 32 + ch) * 8192;
#pragma unroll
  for (int i = 0; i < 4; ++i) {   // full 64x128
    int c = tid + i * 256;
    int ss = c >> 4, dg = c & 15;
    *(int4*)&Qs[ss][dg * 8] = *(const int4*)(Qg + ss * 128 + dg * 8);
  }
  const unsigned short* Sp = Sg + ((size_t)bh * 32 + ch) * 16384;
#pragma unroll
  for (int i = 0; i < 8; ++i) {   // full 128x128
    int c = tid + i * 256;
    int e = c >> 4, dg = c & 15;
    *(int4*)&Ss[e][dg * 8] = *(const int4*)(Sp + e * 128 + dg * 8);
  }
#pragma unroll
  for (int i = 0; i < 2; ++i) {   // full 64x64
    int c = tid + i * 256;
    int t_l = c >> 3, sg = c & 7;
    *(int4*)&As[t_l][sg * 8] =
        *(const int4*)(Ag + ((size_t)bh * 32 + ch) * 4096 + t_l * 64 + sg * 8);
  }
  const unsigned short* Vp = Vg + ((size_t)bh * 32 + ch) * 8192;
#pragma unroll
  for (int i = 0; i < 4; ++i) {   // full 128x64
    int c = tid + i * 256;
    int e = c >> 3, sg = c & 7;
    *(int4*)&Vs[e][sg * 8] = *(const int4*)(Vp + e * 64 + sg * 8);
  }
  if (tid < 128) zc[tid] = zg[((size_t)bh * 32 + ch) * 128 + tid];
  __syncthreads();

  f32x4 nacc[8];
#pragma unroll
  for (int j = 0; j < 8; ++j) nacc[j] = (f32x4){0.f, 0.f, 0.f, 0.f};
#pragma unroll
  for (int kk = 0; kk < 4; ++kk) {
    short8 aq = *(const short8*)&Qs[w * 16 + r][kk * 32 + q * 8];
#pragma unroll
    for (int j = 0; j < 8; ++j) {
      short8 bf = *(const short8*)&Ss[j * 16 + r][kk * 32 + q * 8];
      nacc[j] = __builtin_amdgcn_mfma_f32_16x16x32_bf16(aq, bf, nacc[j], 0, 0, 0);
    }
  }
#pragma unroll
  for (int kk = 0; kk < 2; ++kk) {
    short8 aa = *(const short8*)&As[w * 16 + r][kk * 32 + q * 8];
#pragma unroll
    for (int j = 0; j < 8; ++j) {
      short8 bf = *(const short8*)&Vs[j * 16 + r][kk * 32 + q * 8];
      nacc[j] = __builtin_amdgcn_mfma_f32_16x16x32_bf16(aa, bf, nacc[j], 0, 0, 0);
    }
  }
  // denom for row w*16+r  (w in 0..3: 4 waves cover all 64 rows)
  {
    float dsum = 0.f;
#pragma unroll
    for (int kk = 0; kk < 4; ++kk) {
      short8 aq = *(const short8*)&Qs[w * 16 + r][kk * 32 + q * 8];
      const float* zp = &zc[kk * 32 + q * 8];
      float4 z0a = *(const float4*)zp;
      float4 z0b = *(const float4*)(zp + 4);
      dsum = fmaf(bf2f((unsigned short)aq[0]), z0a.x, dsum);
      dsum = fmaf(bf2f((unsigned short)aq[1]), z0a.y, dsum);
      dsum = fmaf(bf2f((unsigned short)aq[2]), z0a.z, dsum);
      dsum = fmaf(bf2f((unsigned short)aq[3]), z0a.w, dsum);
      dsum = fmaf(bf2f((unsigned short)aq[4]), z0b.x, dsum);
      dsum = fmaf(bf2f((unsigned short)aq[5]), z0b.y, dsum);
      dsum = fmaf(bf2f((unsigned short)aq[6]), z0b.z, dsum);
      dsum = fmaf(bf2f((unsigned short)aq[7]), z0b.w, dsum);
    }
#pragma unroll
    for (int kk = 0; kk < 2; ++kk) {
      short8 aa = *(const short8*)&As[w * 16 + r][kk * 32 + q * 8];
#pragma unroll
      for (int j = 0; j < 8; ++j) dsum += bf2f((unsigned short)aa[j]);
    }
    dsum += __shfl_xor(dsum, 16, 64);
    dsum += __shfl_xor(dsum, 32, 64);
    if (lane < 16) invs[w * 16 + lane] = 1.f / (dsum + 1e-6f);
  }
  __syncthreads();
#pragma unroll
  for (int j = 0; j < 8; ++j) {
#pragma unroll
    for (int rr = 0; rr < 4; ++rr) {
      int t_l = w * 16 + q * 4 + rr;
      size_t m = (size_t)b * 2048 + ch * 64 + t_l;
      numerb[m * 2048 + h * 128 + j * 16 + r] = f2bf(nacc[j][rr] * invs[t_l]);
    }
  }
}

extern "C" void kernel_launch(void* const* d_in, const int* in_sizes, int n_in,
                              void* d_out, int out_size, void* d_ws, size_t ws_size,
                              hipStream_t stream) {
  const float* x  = (const float*)d_in[0];
  const float* Wq = (const float*)d_in[1];
  const float* Wk = (const float*)d_in[2];
  const float* Wv = (const float*)d_in[3];
  const float* Wg = (const float*)d_in[4];
  const float* bg = (const float*)d_in[5];
  const float* Wo = (const float*)d_in[6];
  const float* bo = (const float*)d_in[7];

  char* ws = (char*)d_ws;
  unsigned short* xb    = (unsigned short*)(ws);             // 16.8MB; -> Qt
  unsigned short* Qt    = (unsigned short*)(ws);
  unsigned short* Wt    = (unsigned short*)(ws + 16777216);  // 25.2MB; -> Ktg+Ag
  unsigned short* Ktg   = (unsigned short*)(ws + 16777216);
  unsigned short* Ag    = (unsigned short*)(ws + 33554432);
  unsigned short* Wot   = (unsigned short*)(ws + 41943040);  // 8.4MB
  unsigned short* qkvb  = (unsigned short*)(ws + 50331648);  // 50.3MB; -> Mg
  unsigned short* Mg    = (unsigned short*)(ws + 50331648);  // 33.5MB (Mg->Sg in place)
  float*          mzg   = (float*)(ws + 83886080);           // 0.5MB (mz->zg in place)
  unsigned short* numerb= (unsigned short*)(ws + 100663296); // 16.8MB
  unsigned short* Vg    = (unsigned short*)(ws + 117440512); // 16.8MB
  float*          beta  = (float*)(ws + 134217728);          // 0.26MB
  unsigned short* Wgt16 = (unsigned short*)(ws + 134479872); // 64KB
  float*          gch   = (float*)d_out;                     // 4KB, dies at final gemm

  k_cast<<<8192, 256, 0, stream>>>(x, xb);
  k_transw<<<dim3(32, 32, 5), 256, 0, stream>>>(Wq, Wk, Wv, Wo, Wg, Wt, Wot, Wgt16);
  k_gemm<true, false><<<dim3(48, 32), 256, 0, stream>>>(
      xb, Wt, qkvb, nullptr, 4096, 6144, 2048, 2048, 6144);
  k_betaW<<<1024, 256, 0, stream>>>(xb, Wgt16, bg, beta);
  k_prep<<<dim3(32, 32), 256, 0, stream>>>(qkvb, beta, Qt, Ktg, Ag, Vg, gch);
  k_kv<<<dim3(32, 32), 256, 0, stream>>>(Ktg, Vg, Mg, mzg);
  k_sprefix<<<dim3(8, 32), 256, 0, stream>>>(Mg, mzg, gch);
  k_out<<<dim3(32, 32), 256, 0, stream>>>(Qt, Mg, Ag, Vg, mzg, numerb);
  k_gemm2<false, true><<<dim3(16, 16), 512, 0, stream>>>(
      numerb, Wot, d_out, bo, 4096, 2048, 2048, 2048, 2048);
}